// Round 10
// baseline (1509.164 us; speedup 1.0000x reference)
//
#include <hip/hip_runtime.h>
#include <cfloat>
#include <math.h>

#define B_ 8
#define N_ 4096
#define D_ 64
#define S_ 1024
#define K_ 32
#define CIN_ 131  // 2*D + 3

// ---------------- cross-lane helpers (validated r5-r9) ----------------------
template <int CTRL>
__device__ __forceinline__ unsigned long long dpp_u64(unsigned long long k) {
  int lo = (int)(unsigned int)k, hi = (int)(unsigned int)(k >> 32);
  lo = __builtin_amdgcn_update_dpp(lo, lo, CTRL, 0xf, 0xf, false);
  hi = __builtin_amdgcn_update_dpp(hi, hi, CTRL, 0xf, 0xf, false);
  return ((unsigned long long)(unsigned int)hi << 32) | (unsigned int)lo;
}

template <int CTRL>
__device__ __forceinline__ float dpp_f32(float v) {
  int t = __builtin_amdgcn_update_dpp(__float_as_int(v), __float_as_int(v), CTRL, 0xf, 0xf, false);
  return __int_as_float(t);
}

__device__ __forceinline__ float wave_max_f32_dpp(float v) {
  int x = __float_as_int(v);
#define STEP(ctrl)                                                        \
  {                                                                       \
    int t = __builtin_amdgcn_update_dpp(x, x, ctrl, 0xf, 0xf, false);     \
    v = fmaxf(v, __int_as_float(t));                                      \
    x = __float_as_int(v);                                                \
  }
  STEP(0x111)
  STEP(0x112)
  STEP(0x114)
  STEP(0x118)
  STEP(0x142)
  STEP(0x143)
#undef STEP
  return __int_as_float(__builtin_amdgcn_readlane(x, 63));
}

// relaxed poll + one acquire reload (one cache-invalidate per wait, not per poll)
__device__ __forceinline__ void wait_count(const unsigned int* p, unsigned int val) {
  while (__hip_atomic_load(p, __ATOMIC_RELAXED, __HIP_MEMORY_SCOPE_AGENT) < val)
    __builtin_amdgcn_s_sleep(8);
  (void)__hip_atomic_load(p, __ATOMIC_ACQUIRE, __HIP_MEMORY_SCOPE_AGENT);
}
__device__ __forceinline__ void rel_add(unsigned int* p) {
  __hip_atomic_fetch_add(p, 1u, __ATOMIC_RELEASE, __HIP_MEMORY_SCOPE_AGENT);
}

// ===========================================================================
// STAGE 1 mega-kernel (big-ws path). r9 structure, but static LDS cut from
// 66 KB -> ~17 KB (r9's fatal flaw: fps's 64 KB sp[] mirror was allocated for
// ALL 11784 blocks, capping knn at 2 blocks/CU). fps now has NO coord mirror:
// lanes track local-best coords through the argmax; the winning lane writes
// key+coords; the cross-wave DPP merge carries the float3 payload (this also
// removes the dependent sp[bix] LDS read from the serial chain).
// ===========================================================================
__global__ __launch_bounds__(256) void stage1_kernel(
    const float* __restrict__ xyz, const float* __restrict__ feature,
    int* __restrict__ fps_idx, float* __restrict__ nxyz, float* __restrict__ out0,
    float* __restrict__ featT, int* __restrict__ knn, float* __restrict__ nfeat,
    float* __restrict__ dcache, float* __restrict__ outp,
    unsigned int* __restrict__ flags, unsigned int* __restrict__ kcount,
    unsigned int* __restrict__ gcount, unsigned int* __restrict__ tcount) {
  const int bid = blockIdx.x, tid = threadIdx.x;
  __shared__ __align__(16) float pool[4160];  // 16.6 KB: transpose tile is the max user
  float4* scoord64 = (float4*)pool;                    // [0,256) floats (fps)
  int* si64 = (int*)(pool + 256);                      // [256,320)
  unsigned long long* kbuf = (unsigned long long*)(pool + 320);  // [320,336)
  float4* cbuf = (float4*)(pool + 336);                // [336,368)

  if (bid < 8) {
    // ------------------------- FPS -------------------------
    const int b = bid;
    const float* xb = xyz + (size_t)b * 3 * N_;
    const float4* xv = (const float4*)xb;
    float px[16], py[16], pz[16], dist[16];
#pragma unroll
    for (int q = 0; q < 4; q++) {
      float4 X = xv[4 * tid + q];
      float4 Y = xv[1024 + 4 * tid + q];
      float4 Z = xv[2048 + 4 * tid + q];
      px[4 * q + 0] = X.x; px[4 * q + 1] = X.y; px[4 * q + 2] = X.z; px[4 * q + 3] = X.w;
      py[4 * q + 0] = Y.x; py[4 * q + 1] = Y.y; py[4 * q + 2] = Y.z; py[4 * q + 3] = Y.w;
      pz[4 * q + 0] = Z.x; pz[4 * q + 1] = Z.y; pz[4 * q + 2] = Z.z; pz[4 * q + 3] = Z.w;
    }
#pragma unroll
    for (int i = 0; i < 16; i++) dist[i] = 1e10f;
    if (tid == 0) {
      si64[0] = 0;
      scoord64[0] = make_float4(px[0], py[0], pz[0], 0.f);
    }
    __syncthreads();
    float4 c0 = scoord64[0];
    float cx = c0.x, cy = c0.y, cz = c0.z;
    const int wav = tid >> 6, lane = tid & 63;
    for (int s = 1; s < S_; s++) {
      float best = -1.0f;
      int bi = 16 * tid;
      float bx = px[0], by = py[0], bz = pz[0];
#pragma unroll
      for (int i = 0; i < 16; i++) {
        // no-FMA arithmetic, identical op order to validated rounds
        float dx = __fsub_rn(px[i], cx);
        float dy = __fsub_rn(py[i], cy);
        float dz = __fsub_rn(pz[i], cz);
        float d = __fadd_rn(__fadd_rn(__fmul_rn(dx, dx), __fmul_rn(dy, dy)), __fmul_rn(dz, dz));
        dist[i] = fminf(dist[i], d);
        if (dist[i] > best) {  // strict >: first (= smallest) index
          best = dist[i]; bi = 16 * tid + i;
          bx = px[i]; by = py[i]; bz = pz[i];
        }
      }
      float wmax = wave_max_f32_dpp(best);
      unsigned long long m = __ballot(best == wmax);
      int l = __ffsll(m) - 1;
      if (lane == l) {  // winner lane (lowest lane with best==wmax -> smallest idx)
        kbuf[(s & 1) * 4 + wav] =
            ((unsigned long long)(unsigned int)__float_as_int(best) << 32) |
            (unsigned int)(4095 - bi);
        cbuf[(s & 1) * 4 + wav] = make_float4(bx, by, bz, 0.f);
      }
      __syncthreads();
      // payload-carrying merge of 4 per-wave winners (2 DPP steps)
      unsigned long long k = kbuf[(s & 1) * 4 + (lane & 3)];
      float4 cc = cbuf[(s & 1) * 4 + (lane & 3)];
      {
        unsigned long long t = dpp_u64<0xB1>(k);
        float tx = dpp_f32<0xB1>(cc.x), ty = dpp_f32<0xB1>(cc.y), tz = dpp_f32<0xB1>(cc.z);
        if (t > k) { k = t; cc.x = tx; cc.y = ty; cc.z = tz; }
        t = dpp_u64<0x4E>(k);
        tx = dpp_f32<0x4E>(cc.x); ty = dpp_f32<0x4E>(cc.y); tz = dpp_f32<0x4E>(cc.z);
        if (t > k) { k = t; cc.x = tx; cc.y = ty; cc.z = tz; }
      }
      int bix = 4095 - (int)(k & 0xfffull);
      cx = cc.x; cy = cc.y; cz = cc.z;
      if (tid == 0) {
        si64[s & 63] = bix;
        scoord64[s & 63] = make_float4(cx, cy, cz, 0.f);
      }
      // ---- chunk publication every 64 steps ----
      if ((s & 63) == 63) {
        __syncthreads();
        if (tid < 64) {
          int ss = (s - 63) + tid;
          int gs = b * S_ + ss;
          int n = si64[tid];
          float4 cc2 = scoord64[tid];
          fps_idx[gs] = n;
          nxyz[(size_t)gs * 3 + 0] = cc2.x;
          nxyz[(size_t)gs * 3 + 1] = cc2.y;
          nxyz[(size_t)gs * 3 + 2] = cc2.z;
          out0[(size_t)b * 3 * S_ + ss] = cc2.x;
          out0[(size_t)b * 3 * S_ + S_ + ss] = cc2.y;
          out0[(size_t)b * 3 * S_ + 2 * S_ + ss] = cc2.z;
        }
        __syncthreads();  // all waves drain vmcnt before barrier
        if (tid == 0) {
          __threadfence();
          __hip_atomic_store(&flags[b * 16 + (s >> 6)], 1u, __ATOMIC_RELEASE,
                             __HIP_MEMORY_SCOPE_AGENT);
        }
      }
    }
    return;
  }
  if (bid < 520) {
    // ---------------------- transpose ----------------------
    const int blk = bid - 8;
    const int b = blk >> 6, n0 = (blk & 63) * 64;
    float* tile = pool;  // 64*65 = 4160 floats
#pragma unroll
    for (int i = 0; i < 16; i++) {
      int c = i * 4 + (tid >> 6), nl = tid & 63;
      tile[c * 65 + nl] = feature[((size_t)b * 64 + c) * N_ + n0 + nl];
    }
    __syncthreads();
#pragma unroll
    for (int i = 0; i < 16; i++) {
      int nl = i * 4 + (tid >> 6), c = tid & 63;
      featT[((size_t)b * N_ + n0 + nl) * 64 + c] = tile[c * 65 + nl];
    }
    __syncthreads();
    if (tid == 0) rel_add(tcount);
    return;
  }
  if (bid < 8712) {
    // ------------------------- kNN (r9-validated body) -----
    const int bs = bid - 520;
    if (tid == 0) wait_count(&flags[bs >> 6], 1);
    __syncthreads();
    const int b = bs >> 10;
    const float* xb = xyz + (size_t)b * 3 * N_;
    const float cx = nxyz[(size_t)bs * 3], cy = nxyz[(size_t)bs * 3 + 1],
                cz = nxyz[(size_t)bs * 3 + 2];
    const float cn = __fadd_rn(__fadd_rn(__fmul_rn(cx, cx), __fmul_rn(cy, cy)), __fmul_rn(cz, cz));
    float d[16];
#pragma unroll
    for (int i = 0; i < 16; i++) {
      int n = i * 256 + tid;
      float px = xb[n], py = xb[N_ + n], pz = xb[2 * N_ + n];
      float pn = __fadd_rn(__fadd_rn(__fmul_rn(px, px), __fmul_rn(py, py)), __fmul_rn(pz, pz));
      float dot = __fadd_rn(__fadd_rn(__fmul_rn(cx, px), __fmul_rn(cy, py)), __fmul_rn(cz, pz));
      d[i] = __fsub_rn(__fadd_rn(cn, pn), __fmul_rn(2.0f, dot));
    }
    float mv = FLT_MAX;
    int mi = tid;
#pragma unroll
    for (int i = 0; i < 16; i++)
      if (d[i] < mv) { mv = d[i]; mi = i * 256 + tid; }
    int* skk = si64;
    const int wav = tid >> 6, lane = tid & 63;
    for (int j = 0; j < K_; j++) {
      unsigned int u = __float_as_uint(mv);
      u ^= ((unsigned int)((int)u >> 31) | 0x80000000u);
      unsigned long long key = ((unsigned long long)u << 32) | (unsigned int)mi;
#pragma unroll
      for (int off = 32; off >= 1; off >>= 1) {
        unsigned long long ok = __shfl_xor(key, off);
        if (ok < key) key = ok;
      }
      if (lane == 0) kbuf[(j & 1) * 4 + wav] = key;
      __syncthreads();
      unsigned long long kmin = kbuf[(j & 1) * 4];
#pragma unroll
      for (int w = 1; w < 4; w++) {
        unsigned long long k2 = kbuf[(j & 1) * 4 + w];
        if (k2 < kmin) kmin = k2;
      }
      int g = (int)(kmin & 0xffffffffull);
      if (tid == 0) skk[j] = g;
      if ((g & 255) == tid) {
        int sl = g >> 8;
#pragma unroll
        for (int i = 0; i < 16; i++)
          if (i == sl) d[i] = FLT_MAX;
        mv = FLT_MAX; mi = tid;
#pragma unroll
        for (int i = 0; i < 16; i++)
          if (d[i] < mv) { mv = d[i]; mi = i * 256 + tid; }
      }
    }
    __syncthreads();
    if (tid < K_) knn[(size_t)bs * K_ + tid] = skk[tid];
    __syncthreads();
    if (tid == 0) rel_add(&kcount[bs >> 6]);
    return;
  }
  if (bid < 10760) {
    // ----------------------- gather ------------------------
    const int j = bid - 8712;
    if (tid == 0) {
      wait_count(tcount, 512);
      wait_count(&flags[j >> 4], 1);
    }
    __syncthreads();
    int e = j * 256 + tid;
    int bsx = e >> 6, c = e & 63;
    int bq = bsx >> 10;
    int n = fps_idx[bsx];
    nfeat[e] = featT[((size_t)bq * N_ + n) * 64 + c];
    __syncthreads();
    if (tid == 0) rel_add(&gcount[j >> 4]);
    return;
  }
  {
    // ------------------------ prep (r9-validated body) -----
    const int blk = bid - 10760;
    if (tid == 0) {
      wait_count(tcount, 512);
      wait_count(&kcount[blk >> 3], 64);
      wait_count(&gcount[blk >> 3], 16);
    }
    __syncthreads();
    int* sk = si64;
    float s = 0.f, q = 0.f;
    const int c = tid & 63, qd = tid >> 6;
    for (int g = 0; g < 8; g++) {
      const int bs = blk * 8 + g, b = bs >> 10;
      if (tid < 32) sk[tid] = knn[(size_t)bs * K_ + tid];
      __syncthreads();
      float anc = nfeat[(size_t)bs * 64 + c];
#pragma unroll
      for (int it = 0; it < 8; it++) {
        int kk = it * 4 + qd;
        int n = sk[kk];
        float dd = featT[((size_t)b * N_ + n) * 64 + c] - anc;
        s += dd; q += dd * dd;
        dcache[((size_t)bs * 32 + kk) * 68 + c] = dd;
      }
      if (tid < 96) {
        int c3 = tid >> 5, kk = tid & 31;
        int n = sk[kk];
        float dd = xyz[((size_t)b * 3 + c3) * N_ + n] - nxyz[(size_t)bs * 3 + c3];
        s += dd; q += dd * dd;
        dcache[((size_t)bs * 32 + kk) * 68 + 64 + c3] = dd;
      }
      __syncthreads();
    }
#pragma unroll
    for (int off = 32; off >= 1; off >>= 1) { s += __shfl_xor(s, off); q += __shfl_xor(q, off); }
    float* rs = (float*)kbuf;
    float* rq = rs + 4;
    if ((tid & 63) == 0) { rs[tid >> 6] = s; rq[tid >> 6] = q; }
    __syncthreads();
    if (tid == 0) {
      outp[blk * 2] = rs[0] + rs[1] + rs[2] + rs[3];
      outp[blk * 2 + 1] = rq[0] + rq[1] + rq[2] + rq[3];
    }
  }
}

// ===========================================================================
// ============ FALLBACK (r8) kernels — used when ws is small ================
// ===========================================================================
__global__ __launch_bounds__(256) void fps_kernel(const float* __restrict__ xyz,
                                                  int* __restrict__ fps_idx,
                                                  float* __restrict__ nxyz,
                                                  float* __restrict__ out0) {
  const int tid = threadIdx.x;
  __shared__ __align__(16) float4 sp[N_];
  __shared__ int si[S_];
  __shared__ unsigned long long keyp[2][4];
  const int b = blockIdx.x;
  const float* xb = xyz + (size_t)b * 3 * N_;
  const float4* xv = (const float4*)xb;
  float px[16], py[16], pz[16], dist[16];
#pragma unroll
  for (int q = 0; q < 4; q++) {
    float4 X = xv[4 * tid + q];
    float4 Y = xv[1024 + 4 * tid + q];
    float4 Z = xv[2048 + 4 * tid + q];
    px[4 * q + 0] = X.x; px[4 * q + 1] = X.y; px[4 * q + 2] = X.z; px[4 * q + 3] = X.w;
    py[4 * q + 0] = Y.x; py[4 * q + 1] = Y.y; py[4 * q + 2] = Y.z; py[4 * q + 3] = Y.w;
    pz[4 * q + 0] = Z.x; pz[4 * q + 1] = Z.y; pz[4 * q + 2] = Z.z; pz[4 * q + 3] = Z.w;
  }
#pragma unroll
  for (int i = 0; i < 16; i++) {
    dist[i] = 1e10f;
    sp[16 * tid + i] = make_float4(px[i], py[i], pz[i], 0.f);
  }
  if (tid == 0) si[0] = 0;
  __syncthreads();
  float cx = sp[0].x, cy = sp[0].y, cz = sp[0].z;
  const int wav = tid >> 6, lane = tid & 63;
  for (int s = 1; s < S_; s++) {
    float best = -1.0f;
    int bi = 16 * tid;
#pragma unroll
    for (int i = 0; i < 16; i++) {
      float dx = __fsub_rn(px[i], cx);
      float dy = __fsub_rn(py[i], cy);
      float dz = __fsub_rn(pz[i], cz);
      float d = __fadd_rn(__fadd_rn(__fmul_rn(dx, dx), __fmul_rn(dy, dy)), __fmul_rn(dz, dz));
      dist[i] = fminf(dist[i], d);
      if (dist[i] > best) { best = dist[i]; bi = 16 * tid + i; }
    }
    float wmax = wave_max_f32_dpp(best);
    unsigned long long m = __ballot(best == wmax);
    int l = __ffsll(m) - 1;
    int widx = __builtin_amdgcn_readlane(bi, l);
    if (lane == 0)
      keyp[s & 1][wav] =
          ((unsigned long long)(unsigned int)__float_as_int(wmax) << 32) |
          (unsigned int)(4095 - widx);
    __syncthreads();
    unsigned long long k = keyp[s & 1][lane & 3];
    unsigned long long t;
    t = dpp_u64<0xB1>(k); if (t > k) k = t;
    t = dpp_u64<0x4E>(k); if (t > k) k = t;
    int bix = 4095 - (int)(k & 0xfffull);
    if (tid == 0) si[s] = bix;
    float4 c = sp[bix];
    cx = c.x; cy = c.y; cz = c.z;
  }
  __syncthreads();
  for (int e = tid; e < S_; e += 256) {
    int n = si[e];
    fps_idx[b * S_ + e] = n;
    float4 c = sp[n];
    nxyz[(size_t)(b * S_ + e) * 3 + 0] = c.x;
    nxyz[(size_t)(b * S_ + e) * 3 + 1] = c.y;
    nxyz[(size_t)(b * S_ + e) * 3 + 2] = c.z;
    out0[(size_t)b * 3 * S_ + e] = c.x;
    out0[(size_t)b * 3 * S_ + S_ + e] = c.y;
    out0[(size_t)b * 3 * S_ + 2 * S_ + e] = c.z;
  }
}

__global__ __launch_bounds__(256) void knn_kernel(const float* __restrict__ xyz,
                                                  const float* __restrict__ nxyz,
                                                  int* __restrict__ knn) {
  const int bs = blockIdx.x, tid = threadIdx.x;
  const int b = bs >> 10;
  const float* xb = xyz + (size_t)b * 3 * N_;
  const float cx = nxyz[(size_t)bs * 3], cy = nxyz[(size_t)bs * 3 + 1], cz = nxyz[(size_t)bs * 3 + 2];
  const float cn = __fadd_rn(__fadd_rn(__fmul_rn(cx, cx), __fmul_rn(cy, cy)), __fmul_rn(cz, cz));
  float d[16];
#pragma unroll
  for (int i = 0; i < 16; i++) {
    int n = i * 256 + tid;
    float px = xb[n], py = xb[N_ + n], pz = xb[2 * N_ + n];
    float pn = __fadd_rn(__fadd_rn(__fmul_rn(px, px), __fmul_rn(py, py)), __fmul_rn(pz, pz));
    float dot = __fadd_rn(__fadd_rn(__fmul_rn(cx, px), __fmul_rn(cy, py)), __fmul_rn(cz, pz));
    d[i] = __fsub_rn(__fadd_rn(cn, pn), __fmul_rn(2.0f, dot));
  }
  float mv = FLT_MAX;
  int mi = tid;
#pragma unroll
  for (int i = 0; i < 16; i++)
    if (d[i] < mv) { mv = d[i]; mi = i * 256 + tid; }
  __shared__ unsigned long long keyp[2][4];
  __shared__ int skk[K_];
  const int wav = tid >> 6, lane = tid & 63;
  for (int j = 0; j < K_; j++) {
    unsigned int u = __float_as_uint(mv);
    u ^= ((unsigned int)((int)u >> 31) | 0x80000000u);
    unsigned long long key = ((unsigned long long)u << 32) | (unsigned int)mi;
#pragma unroll
    for (int off = 32; off >= 1; off >>= 1) {
      unsigned long long ok = __shfl_xor(key, off);
      if (ok < key) key = ok;
    }
    if (lane == 0) keyp[j & 1][wav] = key;
    __syncthreads();
    unsigned long long kmin = keyp[j & 1][0];
#pragma unroll
    for (int w = 1; w < 4; w++) {
      unsigned long long k2 = keyp[j & 1][w];
      if (k2 < kmin) kmin = k2;
    }
    int g = (int)(kmin & 0xffffffffull);
    if (tid == 0) skk[j] = g;
    if ((g & 255) == tid) {
      int sl = g >> 8;
#pragma unroll
      for (int i = 0; i < 16; i++)
        if (i == sl) d[i] = FLT_MAX;
      mv = FLT_MAX; mi = tid;
#pragma unroll
      for (int i = 0; i < 16; i++)
        if (d[i] < mv) { mv = d[i]; mi = i * 256 + tid; }
    }
  }
  __syncthreads();
  if (tid < K_) knn[(size_t)bs * K_ + tid] = skk[tid];
}

__global__ __launch_bounds__(256) void gather_nf(const float* __restrict__ feature,
                                                 const int* __restrict__ fps_i,
                                                 float* __restrict__ nfeat) {
  int e = blockIdx.x * 256 + threadIdx.x;
  int b = e >> 16, rem = e & 65535;
  int s = rem >> 6, c = rem & 63;
  int n = fps_i[b * S_ + s];
  nfeat[e] = feature[((size_t)b * 64 + c) * N_ + n];
}

__global__ __launch_bounds__(256) void std_partial(const float* __restrict__ feature,
                                                   const float* __restrict__ xyz,
                                                   const float* __restrict__ nxyz,
                                                   const float* __restrict__ nfeat,
                                                   const int* __restrict__ knn,
                                                   float* __restrict__ outp) {
  const int blk = blockIdx.x, tid = threadIdx.x;
  const int b = blk >> 6, chunk = blk & 63;
  float s = 0.f, q = 0.f;
  for (int e = tid; e < 16 * K_ * 67; e += 256) {
    int so = e / (K_ * 67);
    int rem = e - so * (K_ * 67);
    int kk = rem / 67;
    int c = rem - kk * 67;
    int bs = b * S_ + chunk * 16 + so;
    int n = knn[(size_t)bs * K_ + kk];
    float raw = (c < 64) ? feature[((size_t)b * 64 + c) * N_ + n]
                         : xyz[((size_t)b * 3 + (c - 64)) * N_ + n];
    float anc = (c < 64) ? nfeat[(size_t)bs * 64 + c]
                         : nxyz[(size_t)bs * 3 + (c - 64)];
    float dd = raw - anc;
    s += dd; q += dd * dd;
  }
#pragma unroll
  for (int off = 32; off >= 1; off >>= 1) { s += __shfl_xor(s, off); q += __shfl_xor(q, off); }
  __shared__ float rs[4], rq[4];
  if ((tid & 63) == 0) { rs[tid >> 6] = s; rq[tid >> 6] = q; }
  __syncthreads();
  if (tid == 0) {
    outp[blk * 2] = rs[0] + rs[1] + rs[2] + rs[3];
    outp[blk * 2 + 1] = rq[0] + rq[1] + rq[2] + rq[3];
  }
}

__global__ void std_final(const float* __restrict__ part, float* __restrict__ invstd) {
  int b = threadIdx.x;
  if (b < B_) {
    double s = 0.0, q = 0.0;
    for (int i = 0; i < 64; i++) {
      s += (double)part[(b * 64 + i) * 2];
      q += (double)part[(b * 64 + i) * 2 + 1];
    }
    const double n = (double)(S_ * K_ * 67);
    double var = (q - s * s / n) / (n - 1.0);
    invstd[b] = (float)(1.0 / (sqrt(var) + 1e-5));
  }
}

template <int MODE>
__global__ __launch_bounds__(256, 2) void mlp_kernel(
    const float* __restrict__ feature, const float* __restrict__ xyz,
    const float* __restrict__ nxyz, const float* __restrict__ nfeat,
    const int* __restrict__ knn, const float* __restrict__ invstd,
    const float* __restrict__ alpha, const float* __restrict__ beta,
    const float* __restrict__ w_tr, const float* __restrict__ b_tr,
    const float* __restrict__ w1, const float* __restrict__ b1,
    const float* __restrict__ w2, const float* __restrict__ b2,
    const float* __restrict__ bn_tr, const float* __restrict__ bn_1,
    float* __restrict__ bnpart, float* __restrict__ out1) {
  __shared__ __align__(16) float pool[15556];
  float* Wt = pool;
  float* xin = pool + 8516;
  float* ub = xin;
  float* tb = pool + 8516 + 4192;
  float* part = pool + 8516 + 4192 + 2304;
  int* sknn = (int*)(part + 512);
  const int bs = blockIdx.x, tid = threadIdx.x;
  const int b = bs >> 10, s = bs & 1023;
  if (tid < K_) sknn[tid] = knn[(size_t)bs * K_ + tid];
  for (int e = tid; e < 64 * 131; e += 256) {
    int o = e / 131, c = e - o * 131;
    Wt[c * 65 + o] = w_tr[e];
  }
  __syncthreads();
  const float inv = invstd[b];
  for (int e = tid; e < CIN_ * K_; e += 256) {
    int c = e >> 5, kk = e & 31;
    float v;
    if (c < 67) {
      int n = sknn[kk];
      float raw = (c < 64) ? feature[((size_t)b * 64 + c) * N_ + n]
                           : xyz[((size_t)b * 3 + (c - 64)) * N_ + n];
      float anc = (c < 64) ? nfeat[(size_t)bs * 64 + c]
                           : nxyz[(size_t)bs * 3 + (c - 64)];
      v = alpha[c] * ((raw - anc) * inv) + beta[c];
    } else {
      v = nfeat[(size_t)bs * 64 + (c - 67)];
    }
    xin[e] = v;
  }
  __syncthreads();
  const int o = tid & 63, kkb = (tid >> 6) * 8;
  float acc[8];
  {
    float bv = b_tr[o];
#pragma unroll
    for (int j = 0; j < 8; j++) acc[j] = bv;
  }
  for (int c = 0; c < CIN_; c++) {
    float w = Wt[c * 65 + o];
    const float4 xa = *(const float4*)(xin + c * 32 + kkb);
    const float4 xb4 = *(const float4*)(xin + c * 32 + kkb + 4);
    acc[0] += w * xa.x; acc[1] += w * xa.y; acc[2] += w * xa.z; acc[3] += w * xa.w;
    acc[4] += w * xb4.x; acc[5] += w * xb4.y; acc[6] += w * xb4.z; acc[7] += w * xb4.w;
  }
  if (MODE == 0) {
    float s8 = 0.f, q8 = 0.f;
#pragma unroll
    for (int j = 0; j < 8; j++) { s8 += acc[j]; q8 += acc[j] * acc[j]; }
    part[(tid >> 6) * 64 + o] = s8;
    part[256 + (tid >> 6) * 64 + o] = q8;
    __syncthreads();
    if (tid < 64) {
      float ss = 0.f, qq = 0.f;
      for (int g = 0; g < 4; g++) { ss += part[g * 64 + tid]; qq += part[256 + g * 64 + tid]; }
      bnpart[(size_t)bs * 128 + tid] = ss;
      bnpart[(size_t)bs * 128 + 64 + tid] = qq;
    }
    return;
  }
  float tv[8];
  {
    float sc = bn_tr[o], sh = bn_tr[64 + o];
#pragma unroll
    for (int j = 0; j < 8; j++) {
      tv[j] = fmaxf(fmaf(sc, acc[j], sh), 0.f);
      tb[o * 36 + kkb + j] = tv[j];
    }
  }
  __syncthreads();
  for (int e = tid; e < 64 * 64; e += 256) {
    int oo = e >> 6, c = e & 63;
    Wt[c * 65 + oo] = w1[e];
  }
  __syncthreads();
  float acc2[8];
  {
    float bv = b1[o];
#pragma unroll
    for (int j = 0; j < 8; j++) acc2[j] = bv;
  }
  for (int c = 0; c < 64; c++) {
    float w = Wt[c * 65 + o];
    const float4 ta = *(const float4*)(tb + c * 36 + kkb);
    const float4 ta2 = *(const float4*)(tb + c * 36 + kkb + 4);
    acc2[0] += w * ta.x; acc2[1] += w * ta.y; acc2[2] += w * ta.z; acc2[3] += w * ta.w;
    acc2[4] += w * ta2.x; acc2[5] += w * ta2.y; acc2[6] += w * ta2.z; acc2[7] += w * ta2.w;
  }
  if (MODE == 1) {
    float s8 = 0.f, q8 = 0.f;
#pragma unroll
    for (int j = 0; j < 8; j++) { s8 += acc2[j]; q8 += acc2[j] * acc2[j]; }
    part[(tid >> 6) * 64 + o] = s8;
    part[256 + (tid >> 6) * 64 + o] = q8;
    __syncthreads();
    if (tid < 64) {
      float ss = 0.f, qq = 0.f;
      for (int g = 0; g < 4; g++) { ss += part[g * 64 + tid]; qq += part[256 + g * 64 + tid]; }
      bnpart[(size_t)bs * 128 + tid] = ss;
      bnpart[(size_t)bs * 128 + 64 + tid] = qq;
    }
    return;
  }
  {
    float sc = bn_1[o], sh = bn_1[64 + o];
#pragma unroll
    for (int j = 0; j < 8; j++) ub[o * 36 + kkb + j] = fmaxf(fmaf(sc, acc2[j], sh), 0.f);
  }
  __syncthreads();
  for (int e = tid; e < 64 * 64; e += 256) {
    int oo = e >> 6, c = e & 63;
    Wt[c * 65 + oo] = w2[e];
  }
  __syncthreads();
  float acc3[8];
  {
    float bv = b2[o];
#pragma unroll
    for (int j = 0; j < 8; j++) acc3[j] = bv;
  }
  for (int c = 0; c < 64; c++) {
    float w = Wt[c * 65 + o];
    const float4 ua = *(const float4*)(ub + c * 36 + kkb);
    const float4 ua2 = *(const float4*)(ub + c * 36 + kkb + 4);
    acc3[0] += w * ua.x; acc3[1] += w * ua.y; acc3[2] += w * ua.z; acc3[3] += w * ua.w;
    acc3[4] += w * ua2.x; acc3[5] += w * ua2.y; acc3[6] += w * ua2.z; acc3[7] += w * ua2.w;
  }
  float m = 0.f;
#pragma unroll
  for (int j = 0; j < 8; j++) m = fmaxf(m, fmaxf(acc3[j] + tv[j], 0.f));
  part[(tid >> 6) * 64 + o] = m;
  __syncthreads();
  if (tid < 64) {
    float mm = part[tid];
    for (int g = 1; g < 4; g++) mm = fmaxf(mm, part[g * 64 + tid]);
    out1[((size_t)b * 64 + tid) * S_ + s] = mm;
  }
}

// ---------------------------------------------------------------------------
// BN finalize (shared by both paths).
// ---------------------------------------------------------------------------
__global__ __launch_bounds__(256) void bn_finalize(const float* __restrict__ part,
                                                   const float* __restrict__ g,
                                                   const float* __restrict__ be,
                                                   float* __restrict__ bnout) {
  const int ch = blockIdx.x, tid = threadIdx.x;
  double s = 0.0, q = 0.0;
  for (int i = tid; i < B_ * S_; i += 256) {
    s += (double)part[(size_t)i * 128 + ch];
    q += (double)part[(size_t)i * 128 + 64 + ch];
  }
#pragma unroll
  for (int off = 32; off >= 1; off >>= 1) { s += __shfl_xor(s, off); q += __shfl_xor(q, off); }
  __shared__ double ls[4], lq[4];
  if ((tid & 63) == 0) { ls[tid >> 6] = s; lq[tid >> 6] = q; }
  __syncthreads();
  if (tid == 0) {
    double Ssum = ls[0] + ls[1] + ls[2] + ls[3];
    double Qsum = lq[0] + lq[1] + lq[2] + lq[3];
    const double n = (double)(B_ * S_ * K_);
    double mu = Ssum / n;
    double var = Qsum / n - mu * mu;
    double sc = (double)g[ch] / sqrt(var + 1e-5);
    bnout[ch] = (float)sc;
    bnout[64 + ch] = (float)((double)be[ch] - mu * sc);
  }
}

// ===========================================================================
// ================== CACHE-PATH tail kernels (validated r7/r8) ==============
// ===========================================================================
__global__ void std_final_c(const float* __restrict__ part, float* __restrict__ invstd) {
  int b = threadIdx.x;
  if (b < B_) {
    double s = 0.0, q = 0.0;
    for (int i = 0; i < 128; i++) {
      s += (double)part[(b * 128 + i) * 2];
      q += (double)part[(b * 128 + i) * 2 + 1];
    }
    const double n = (double)(S_ * K_ * 67);
    double var = (q - s * s / n) / (n - 1.0);
    invstd[b] = (float)(1.0 / (sqrt(var) + 1e-5));
  }
}

__global__ __launch_bounds__(256, 2) void mlp0c(
    const float* __restrict__ dcache, const float* __restrict__ nfeat,
    const float* __restrict__ invstd,
    const float* __restrict__ alpha, const float* __restrict__ beta,
    const float* __restrict__ w_tr, const float* __restrict__ b_tr,
    float* __restrict__ bnpart, float* __restrict__ tcache) {
  __shared__ __align__(16) float pool[13220];
  float* Wt = pool;
  float* xin = pool + 8516;
  float* part = pool + 8516 + 4192;
  const int bs = blockIdx.x, tid = threadIdx.x;
  const int b = bs >> 10;
  for (int e = tid; e < 64 * 131; e += 256) {
    int o = e / 131, c = e - o * 131;
    Wt[c * 65 + o] = w_tr[e];
  }
  const float inv = invstd[b];
  {
    const int c = tid & 63, qd = tid >> 6;
    float al = alpha[c], bev = beta[c];
#pragma unroll
    for (int it = 0; it < 8; it++) {
      int kk = it * 4 + qd;
      xin[c * 32 + kk] = al * (dcache[((size_t)bs * 32 + kk) * 68 + c] * inv) + bev;
    }
    if (tid < 96) {
      int c3 = 64 + (tid >> 5), kk = tid & 31;
      xin[c3 * 32 + kk] =
          alpha[c3] * (dcache[((size_t)bs * 32 + kk) * 68 + c3] * inv) + beta[c3];
    }
    for (int e = tid; e < 2048; e += 256) {
      int cc = 67 + (e >> 5), kk = e & 31;
      xin[cc * 32 + kk] = nfeat[(size_t)bs * 64 + (e >> 5)];
    }
  }
  __syncthreads();
  const int o = tid & 63, kkb = (tid >> 6) * 8;
  float acc[8];
  {
    float bv = b_tr[o];
#pragma unroll
    for (int j = 0; j < 8; j++) acc[j] = bv;
  }
  for (int c = 0; c < CIN_; c++) {
    float w = Wt[c * 65 + o];
    const float4 xa = *(const float4*)(xin + c * 32 + kkb);
    const float4 xb4 = *(const float4*)(xin + c * 32 + kkb + 4);
    acc[0] += w * xa.x; acc[1] += w * xa.y; acc[2] += w * xa.z; acc[3] += w * xa.w;
    acc[4] += w * xb4.x; acc[5] += w * xb4.y; acc[6] += w * xb4.z; acc[7] += w * xb4.w;
  }
  {
    float4* tp = (float4*)(tcache + ((size_t)bs * 64 + o) * 32 + kkb);
    tp[0] = make_float4(acc[0], acc[1], acc[2], acc[3]);
    tp[1] = make_float4(acc[4], acc[5], acc[6], acc[7]);
  }
  float s8 = 0.f, q8 = 0.f;
#pragma unroll
  for (int j = 0; j < 8; j++) { s8 += acc[j]; q8 += acc[j] * acc[j]; }
  part[(tid >> 6) * 64 + o] = s8;
  part[256 + (tid >> 6) * 64 + o] = q8;
  __syncthreads();
  if (tid < 64) {
    float ss = 0.f, qq = 0.f;
    for (int g = 0; g < 4; g++) { ss += part[g * 64 + tid]; qq += part[256 + g * 64 + tid]; }
    bnpart[(size_t)bs * 128 + tid] = ss;
    bnpart[(size_t)bs * 128 + 64 + tid] = qq;
  }
}

__global__ __launch_bounds__(256, 3) void mlp1c(
    const float* __restrict__ tcache, const float* __restrict__ bn_tr,
    const float* __restrict__ w1, const float* __restrict__ b1,
    float* __restrict__ bnpart, float* __restrict__ ucache) {
  __shared__ __align__(16) float pool[6976];
  float* Wt = pool;
  float* tb = pool + 4160;
  float* part = pool + 4160 + 2304;
  const int bs = blockIdx.x, tid = threadIdx.x;
  const int o = tid & 63, kkb = (tid >> 6) * 8;
  for (int e = tid; e < 64 * 64; e += 256) {
    int oo = e >> 6, c = e & 63;
    Wt[c * 65 + oo] = w1[e];
  }
  float t[8];
  {
    const float4* tp = (const float4*)(tcache + ((size_t)bs * 64 + o) * 32 + kkb);
    float4 a = tp[0], b4 = tp[1];
    t[0] = a.x; t[1] = a.y; t[2] = a.z; t[3] = a.w;
    t[4] = b4.x; t[5] = b4.y; t[6] = b4.z; t[7] = b4.w;
  }
  {
    float sc = bn_tr[o], sh = bn_tr[64 + o];
#pragma unroll
    for (int j = 0; j < 8; j++) tb[o * 36 + kkb + j] = fmaxf(fmaf(sc, t[j], sh), 0.f);
  }
  __syncthreads();
  float acc2[8];
  {
    float bv = b1[o];
#pragma unroll
    for (int j = 0; j < 8; j++) acc2[j] = bv;
  }
  for (int c = 0; c < 64; c++) {
    float w = Wt[c * 65 + o];
    const float4 ta = *(const float4*)(tb + c * 36 + kkb);
    const float4 ta2 = *(const float4*)(tb + c * 36 + kkb + 4);
    acc2[0] += w * ta.x; acc2[1] += w * ta.y; acc2[2] += w * ta.z; acc2[3] += w * ta.w;
    acc2[4] += w * ta2.x; acc2[5] += w * ta2.y; acc2[6] += w * ta2.z; acc2[7] += w * ta2.w;
  }
  {
    float4* up = (float4*)(ucache + ((size_t)bs * 64 + o) * 32 + kkb);
    up[0] = make_float4(acc2[0], acc2[1], acc2[2], acc2[3]);
    up[1] = make_float4(acc2[4], acc2[5], acc2[6], acc2[7]);
  }
  float s8 = 0.f, q8 = 0.f;
#pragma unroll
  for (int j = 0; j < 8; j++) { s8 += acc2[j]; q8 += acc2[j] * acc2[j]; }
  part[(tid >> 6) * 64 + o] = s8;
  part[256 + (tid >> 6) * 64 + o] = q8;
  __syncthreads();
  if (tid < 64) {
    float ss = 0.f, qq = 0.f;
    for (int g = 0; g < 4; g++) { ss += part[g * 64 + tid]; qq += part[256 + g * 64 + tid]; }
    bnpart[(size_t)bs * 128 + tid] = ss;
    bnpart[(size_t)bs * 128 + 64 + tid] = qq;
  }
}

__global__ __launch_bounds__(256, 3) void mlp2c(
    const float* __restrict__ tcache, const float* __restrict__ ucache,
    const float* __restrict__ bn_tr, const float* __restrict__ bn_1,
    const float* __restrict__ w2, const float* __restrict__ b2,
    float* __restrict__ out1) {
  __shared__ __align__(16) float pool[6976];
  float* Wt = pool;
  float* ub = pool + 4160;
  float* part = pool + 4160 + 2304;
  const int bs = blockIdx.x, tid = threadIdx.x;
  const int b = bs >> 10, s = bs & 1023;
  const int o = tid & 63, kkb = (tid >> 6) * 8;
  for (int e = tid; e < 64 * 64; e += 256) {
    int oo = e >> 6, c = e & 63;
    Wt[c * 65 + oo] = w2[e];
  }
  {
    const float4* up = (const float4*)(ucache + ((size_t)bs * 64 + o) * 32 + kkb);
    float4 a = up[0], b4 = up[1];
    float u[8] = {a.x, a.y, a.z, a.w, b4.x, b4.y, b4.z, b4.w};
    float sc = bn_1[o], sh = bn_1[64 + o];
#pragma unroll
    for (int j = 0; j < 8; j++) ub[o * 36 + kkb + j] = fmaxf(fmaf(sc, u[j], sh), 0.f);
  }
  __syncthreads();
  float acc3[8];
  {
    float bv = b2[o];
#pragma unroll
    for (int j = 0; j < 8; j++) acc3[j] = bv;
  }
  for (int c = 0; c < 64; c++) {
    float w = Wt[c * 65 + o];
    const float4 ua = *(const float4*)(ub + c * 36 + kkb);
    const float4 ua2 = *(const float4*)(ub + c * 36 + kkb + 4);
    acc3[0] += w * ua.x; acc3[1] += w * ua.y; acc3[2] += w * ua.z; acc3[3] += w * ua.w;
    acc3[4] += w * ua2.x; acc3[5] += w * ua2.y; acc3[6] += w * ua2.z; acc3[7] += w * ua2.w;
  }
  float tv[8];
  {
    const float4* tp = (const float4*)(tcache + ((size_t)bs * 64 + o) * 32 + kkb);
    float4 a = tp[0], b4 = tp[1];
    float t[8] = {a.x, a.y, a.z, a.w, b4.x, b4.y, b4.z, b4.w};
    float sc = bn_tr[o], sh = bn_tr[64 + o];
#pragma unroll
    for (int j = 0; j < 8; j++) tv[j] = fmaxf(fmaf(sc, t[j], sh), 0.f);
  }
  float m = 0.f;
#pragma unroll
  for (int j = 0; j < 8; j++) m = fmaxf(m, fmaxf(acc3[j] + tv[j], 0.f));
  part[(tid >> 6) * 64 + o] = m;
  __syncthreads();
  if (tid < 64) {
    float mm = part[tid];
    for (int g = 1; g < 4; g++) mm = fmaxf(mm, part[g * 64 + tid]);
    out1[((size_t)b * 64 + tid) * S_ + s] = mm;
  }
}

// ---------------------------------------------------------------------------
extern "C" void kernel_launch(void* const* d_in, const int* in_sizes, int n_in,
                              void* d_out, int out_size, void* d_ws, size_t ws_size,
                              hipStream_t stream) {
  const float* xyz = (const float*)d_in[0];
  const float* feature = (const float*)d_in[1];
  const float* alpha = (const float*)d_in[2];
  const float* beta = (const float*)d_in[3];
  const float* w_tr = (const float*)d_in[4];
  const float* b_tr = (const float*)d_in[5];
  const float* g_tr = (const float*)d_in[6];
  const float* be_tr = (const float*)d_in[7];
  const float* w1 = (const float*)d_in[8];
  const float* b1 = (const float*)d_in[9];
  const float* g1 = (const float*)d_in[10];
  const float* be1 = (const float*)d_in[11];
  const float* w2 = (const float*)d_in[12];
  const float* b2 = (const float*)d_in[13];

  char* ws = (char*)d_ws;
  int* fps_i = (int*)(ws);                      // 32768 B
  float* nxyz = (float*)(ws + 32768);           // 98304 B
  float* nfeat = (float*)(ws + 131072);         // 2097152 B
  int* knn = (int*)(ws + 2228224);              // 1048576 B
  float* stdpart = (float*)(ws + 3276800);      // 4096 B (fallback)
  float* invstd = (float*)(ws + 3280896);       // 64 B
  float* bn_tr = (float*)(ws + 3280960);        // 512 B
  float* bn_1 = (float*)(ws + 3281472);         // 512 B
  float* bnpart = (float*)(ws + 3281984);       // 4194304 B -> end 7476288
  float* featT = (float*)(ws + 7476288);        // 8388608 B
  float* dcache = (float*)(ws + 15864896);      // 71303168 B
  float* tcache = (float*)(ws + 87168064);      // 67108864 B
  float* ucache = (float*)(ws + 154276928);     // 67108864 B
  float* stdpart_c = (float*)(ws + 221385792);  // 8192 B -> 221393984
  unsigned int* flags = (unsigned int*)(ws + 221393984);   // 512 B
  unsigned int* kcount = (unsigned int*)(ws + 221394496);  // 512 B
  unsigned int* gcount = (unsigned int*)(ws + 221395008);  // 512 B
  unsigned int* tcount = (unsigned int*)(ws + 221395520);  // 64 B -> 221395584

  float* out0 = (float*)d_out;
  float* out1 = out0 + B_ * 3 * S_;

  const bool big = (ws_size >= 221395584ull);

  if (big) {
    hipMemsetAsync(ws + 221393984, 0, 1600, stream);
    stage1_kernel<<<8 + 512 + 8192 + 2048 + 1024, 256, 0, stream>>>(
        xyz, feature, fps_i, nxyz, out0, featT, knn, nfeat, dcache, stdpart_c,
        flags, kcount, gcount, tcount);
    std_final_c<<<1, 64, 0, stream>>>(stdpart_c, invstd);
    mlp0c<<<B_ * S_, 256, 0, stream>>>(dcache, nfeat, invstd, alpha, beta, w_tr, b_tr,
                                       bnpart, tcache);
    bn_finalize<<<64, 256, 0, stream>>>(bnpart, g_tr, be_tr, bn_tr);
    mlp1c<<<B_ * S_, 256, 0, stream>>>(tcache, bn_tr, w1, b1, bnpart, ucache);
    bn_finalize<<<64, 256, 0, stream>>>(bnpart, g1, be1, bn_1);
    mlp2c<<<B_ * S_, 256, 0, stream>>>(tcache, ucache, bn_tr, bn_1, w2, b2, out1);
  } else {
    fps_kernel<<<8, 256, 0, stream>>>(xyz, fps_i, nxyz, out0);
    gather_nf<<<(B_ * S_ * D_) / 256, 256, 0, stream>>>(feature, fps_i, nfeat);
    knn_kernel<<<8192, 256, 0, stream>>>(xyz, nxyz, knn);
    std_partial<<<B_ * 64, 256, 0, stream>>>(feature, xyz, nxyz, nfeat, knn, stdpart);
    std_final<<<1, 64, 0, stream>>>(stdpart, invstd);
    mlp_kernel<0><<<B_ * S_, 256, 0, stream>>>(feature, xyz, nxyz, nfeat, knn, invstd,
                                               alpha, beta, w_tr, b_tr, w1, b1, w2, b2,
                                               bn_tr, bn_1, bnpart, out1);
    bn_finalize<<<64, 256, 0, stream>>>(bnpart, g_tr, be_tr, bn_tr);
    mlp_kernel<1><<<B_ * S_, 256, 0, stream>>>(feature, xyz, nxyz, nfeat, knn, invstd,
                                               alpha, beta, w_tr, b_tr, w1, b1, w2, b2,
                                               bn_tr, bn_1, bnpart, out1);
    bn_finalize<<<64, 256, 0, stream>>>(bnpart, g1, be1, bn_1);
    mlp_kernel<2><<<B_ * S_, 256, 0, stream>>>(feature, xyz, nxyz, nfeat, knn, invstd,
                                               alpha, beta, w_tr, b_tr, w1, b1, w2, b2,
                                               bn_tr, bn_1, bnpart, out1);
  }
}

// Round 12
// 1168.321 us; speedup vs baseline: 1.2917x; 1.2917x over previous
//
#include <hip/hip_runtime.h>
#include <cfloat>
#include <math.h>

#define B_ 8
#define N_ 4096
#define D_ 64
#define S_ 1024
#define K_ 32
#define CIN_ 131  // 2*D + 3

// Move a u64 across lanes with a constant DPP control (2x 32-bit update_dpp).
template <int CTRL>
__device__ __forceinline__ unsigned long long dpp_u64(unsigned long long k) {
  int lo = (int)(unsigned int)k, hi = (int)(unsigned int)(k >> 32);
  lo = __builtin_amdgcn_update_dpp(lo, lo, CTRL, 0xf, 0xf, false);
  hi = __builtin_amdgcn_update_dpp(hi, hi, CTRL, 0xf, 0xf, false);
  return ((unsigned long long)(unsigned int)hi << 32) | (unsigned int)lo;
}

// Wave(64)-wide float max via DPP (VALU pipe). Result broadcast via readlane 63.
__device__ __forceinline__ float wave_max_f32_dpp(float v) {
  int x = __float_as_int(v);
#define STEP(ctrl)                                                        \
  {                                                                       \
    int t = __builtin_amdgcn_update_dpp(x, x, ctrl, 0xf, 0xf, false);     \
    v = fmaxf(v, __int_as_float(t));                                      \
    x = __float_as_int(v);                                                \
  }
  STEP(0x111)
  STEP(0x112)
  STEP(0x114)
  STEP(0x118)
  STEP(0x142)
  STEP(0x143)
#undef STEP
  return __int_as_float(__builtin_amdgcn_readlane(x, 63));
}

// ---------------------------------------------------------------------------
// FPS: blocks 0..7 do FPS (256 threads, thread t owns contiguous [16t,16t+16)).
// Blocks 8..519 transpose feature [b][c][n] -> featT [b][n][c] (independent
// work fused into this dispatch; reuses sp[] LDS as the 64x65 tile).
// Per FPS step: local argmax -> DPP wave max + ballot resolve -> lane-0
// writes packed u64 winner -> ONE barrier -> read keyp[lane&3], 2 DPP-step
// merge -> next centroid from LDS. No global ops in the loop.
// (r8-validated: 610 us, banked. r9-r11 overlap attempts all regressed or
// deadlocked — the producer/consumer mega-kernel depends on dispatch order,
// which is undefined. Do not resurrect without cooperative launch.)
// ---------------------------------------------------------------------------
__global__ __launch_bounds__(256) void fps_kernel(const float* __restrict__ xyz,
                                                  int* __restrict__ fps_idx,
                                                  float* __restrict__ nxyz,
                                                  float* __restrict__ out0,
                                                  const float* __restrict__ feature,
                                                  float* __restrict__ featT) {
  const int tid = threadIdx.x;
  __shared__ __align__(16) float4 sp[N_];    // 64 KB coord mirror / transpose tile
  __shared__ int si[S_];
  __shared__ unsigned long long keyp[2][4];
  if (blockIdx.x >= 8) {
    // ---- fused transpose ----
    const int blk = blockIdx.x - 8;
    const int b = blk >> 6, n0 = (blk & 63) * 64;
    float* tile = (float*)sp;  // 64*65 floats
#pragma unroll
    for (int i = 0; i < 16; i++) {
      int c = i * 4 + (tid >> 6), nl = tid & 63;
      tile[c * 65 + nl] = feature[((size_t)b * 64 + c) * N_ + n0 + nl];
    }
    __syncthreads();
#pragma unroll
    for (int i = 0; i < 16; i++) {
      int nl = i * 4 + (tid >> 6), c = tid & 63;
      featT[((size_t)b * N_ + n0 + nl) * 64 + c] = tile[c * 65 + nl];
    }
    return;
  }
  const int b = blockIdx.x;
  const float* xb = xyz + (size_t)b * 3 * N_;
  const float4* xv = (const float4*)xb;
  float px[16], py[16], pz[16], dist[16];
#pragma unroll
  for (int q = 0; q < 4; q++) {
    float4 X = xv[4 * tid + q];
    float4 Y = xv[1024 + 4 * tid + q];
    float4 Z = xv[2048 + 4 * tid + q];
    px[4 * q + 0] = X.x; px[4 * q + 1] = X.y; px[4 * q + 2] = X.z; px[4 * q + 3] = X.w;
    py[4 * q + 0] = Y.x; py[4 * q + 1] = Y.y; py[4 * q + 2] = Y.z; py[4 * q + 3] = Y.w;
    pz[4 * q + 0] = Z.x; pz[4 * q + 1] = Z.y; pz[4 * q + 2] = Z.z; pz[4 * q + 3] = Z.w;
  }
#pragma unroll
  for (int i = 0; i < 16; i++) {
    dist[i] = 1e10f;
    sp[16 * tid + i] = make_float4(px[i], py[i], pz[i], 0.f);
  }
  if (tid == 0) si[0] = 0;
  __syncthreads();
  float cx = sp[0].x, cy = sp[0].y, cz = sp[0].z;
  const int wav = tid >> 6, lane = tid & 63;
  for (int s = 1; s < S_; s++) {
    float best = -1.0f;
    int bi = 16 * tid;
#pragma unroll
    for (int i = 0; i < 16; i++) {
      // no-FMA arithmetic, identical op order to validated rounds
      float dx = __fsub_rn(px[i], cx);
      float dy = __fsub_rn(py[i], cy);
      float dz = __fsub_rn(pz[i], cz);
      float d = __fadd_rn(__fadd_rn(__fmul_rn(dx, dx), __fmul_rn(dy, dy)), __fmul_rn(dz, dz));
      dist[i] = fminf(dist[i], d);
      if (dist[i] > best) { best = dist[i]; bi = 16 * tid + i; }  // strict >: smallest idx
    }
    float wmax = wave_max_f32_dpp(best);
    unsigned long long m = __ballot(best == wmax);
    int l = __ffsll(m) - 1;
    int widx = __builtin_amdgcn_readlane(bi, l);
    if (lane == 0)
      keyp[s & 1][wav] =
          ((unsigned long long)(unsigned int)__float_as_int(wmax) << 32) |
          (unsigned int)(4095 - widx);
    __syncthreads();
    // merge 4 per-wave winners: 1 LDS read + 2 DPP steps (period-4 in quads)
    unsigned long long k = keyp[s & 1][lane & 3];
    unsigned long long t;
    t = dpp_u64<0xB1>(k); if (t > k) k = t;  // quad_perm xor 1
    t = dpp_u64<0x4E>(k); if (t > k) k = t;  // quad_perm xor 2
    int bix = 4095 - (int)(k & 0xfffull);
    if (tid == 0) si[s] = bix;
    float4 c = sp[bix];
    cx = c.x; cy = c.y; cz = c.z;
  }
  __syncthreads();
  for (int e = tid; e < S_; e += 256) {
    int n = si[e];
    fps_idx[b * S_ + e] = n;
    float4 c = sp[n];
    nxyz[(size_t)(b * S_ + e) * 3 + 0] = c.x;
    nxyz[(size_t)(b * S_ + e) * 3 + 1] = c.y;
    nxyz[(size_t)(b * S_ + e) * 3 + 2] = c.z;
    out0[(size_t)b * 3 * S_ + e] = c.x;
    out0[(size_t)b * 3 * S_ + S_ + e] = c.y;
    out0[(size_t)b * 3 * S_ + 2 * S_ + e] = c.z;
  }
}

// ---------------------------------------------------------------------------
// kNN (validated inner logic). Blocks >= 8192 perform the fused
// anchor-feature gather from featT.
// ---------------------------------------------------------------------------
__global__ __launch_bounds__(256) void knn_kernel(const float* __restrict__ xyz,
                                                  const float* __restrict__ nxyz,
                                                  int* __restrict__ knn,
                                                  const float* __restrict__ featT,
                                                  const int* __restrict__ fps_i,
                                                  float* __restrict__ nfeat) {
  const int bs = blockIdx.x, tid = threadIdx.x;
  if (bs >= 8192) {
    int e = (bs - 8192) * 256 + tid;  // < B*S*D
    int bsx = e >> 6, c = e & 63;
    int bq = bsx >> 10;
    int n = fps_i[bsx];
    nfeat[e] = featT[((size_t)bq * N_ + n) * 64 + c];
    return;
  }
  const int b = bs >> 10;
  const float* xb = xyz + (size_t)b * 3 * N_;
  const float cx = nxyz[(size_t)bs * 3], cy = nxyz[(size_t)bs * 3 + 1], cz = nxyz[(size_t)bs * 3 + 2];
  const float cn = __fadd_rn(__fadd_rn(__fmul_rn(cx, cx), __fmul_rn(cy, cy)), __fmul_rn(cz, cz));
  float d[16];
#pragma unroll
  for (int i = 0; i < 16; i++) {
    int n = i * 256 + tid;
    float px = xb[n], py = xb[N_ + n], pz = xb[2 * N_ + n];
    float pn = __fadd_rn(__fadd_rn(__fmul_rn(px, px), __fmul_rn(py, py)), __fmul_rn(pz, pz));
    float dot = __fadd_rn(__fadd_rn(__fmul_rn(cx, px), __fmul_rn(cy, py)), __fmul_rn(cz, pz));
    d[i] = __fsub_rn(__fadd_rn(cn, pn), __fmul_rn(2.0f, dot));
  }
  float mv = FLT_MAX;
  int mi = tid;
#pragma unroll
  for (int i = 0; i < 16; i++)
    if (d[i] < mv) { mv = d[i]; mi = i * 256 + tid; }
  __shared__ unsigned long long keyp[2][4];
  __shared__ int skk[K_];
  const int wav = tid >> 6, lane = tid & 63;
  for (int j = 0; j < K_; j++) {
    unsigned int u = __float_as_uint(mv);
    u ^= ((unsigned int)((int)u >> 31) | 0x80000000u);
    unsigned long long key = ((unsigned long long)u << 32) | (unsigned int)mi;
#pragma unroll
    for (int off = 32; off >= 1; off >>= 1) {
      unsigned long long ok = __shfl_xor(key, off);
      if (ok < key) key = ok;
    }
    if (lane == 0) keyp[j & 1][wav] = key;
    __syncthreads();
    unsigned long long kmin = keyp[j & 1][0];
#pragma unroll
    for (int w = 1; w < 4; w++) {
      unsigned long long k2 = keyp[j & 1][w];
      if (k2 < kmin) kmin = k2;
    }
    int g = (int)(kmin & 0xffffffffull);
    if (tid == 0) skk[j] = g;
    if ((g & 255) == tid) {
      int sl = g >> 8;
#pragma unroll
      for (int i = 0; i < 16; i++)
        if (i == sl) d[i] = FLT_MAX;
      mv = FLT_MAX; mi = tid;
#pragma unroll
      for (int i = 0; i < 16; i++)
        if (d[i] < mv) { mv = d[i]; mi = i * 256 + tid; }
    }
  }
  __syncthreads();
  if (tid < K_) knn[(size_t)bs * K_ + tid] = skk[tid];
}

// ===========================================================================
// ============ FALLBACK (r6) kernels — used when ws is small ================
// ===========================================================================
__global__ __launch_bounds__(256) void gather_nf(const float* __restrict__ feature,
                                                 const int* __restrict__ fps_i,
                                                 float* __restrict__ nfeat) {
  int e = blockIdx.x * 256 + threadIdx.x;
  int b = e >> 16, rem = e & 65535;
  int s = rem >> 6, c = rem & 63;
  int n = fps_i[b * S_ + s];
  nfeat[e] = feature[((size_t)b * 64 + c) * N_ + n];
}

__global__ __launch_bounds__(256) void std_partial(const float* __restrict__ feature,
                                                   const float* __restrict__ xyz,
                                                   const float* __restrict__ nxyz,
                                                   const float* __restrict__ nfeat,
                                                   const int* __restrict__ knn,
                                                   float* __restrict__ outp) {
  const int blk = blockIdx.x, tid = threadIdx.x;
  const int b = blk >> 6, chunk = blk & 63;
  float s = 0.f, q = 0.f;
  for (int e = tid; e < 16 * K_ * 67; e += 256) {
    int so = e / (K_ * 67);
    int rem = e - so * (K_ * 67);
    int kk = rem / 67;
    int c = rem - kk * 67;
    int bs = b * S_ + chunk * 16 + so;
    int n = knn[(size_t)bs * K_ + kk];
    float raw = (c < 64) ? feature[((size_t)b * 64 + c) * N_ + n]
                         : xyz[((size_t)b * 3 + (c - 64)) * N_ + n];
    float anc = (c < 64) ? nfeat[(size_t)bs * 64 + c]
                         : nxyz[(size_t)bs * 3 + (c - 64)];
    float dd = raw - anc;
    s += dd; q += dd * dd;
  }
#pragma unroll
  for (int off = 32; off >= 1; off >>= 1) { s += __shfl_xor(s, off); q += __shfl_xor(q, off); }
  __shared__ float rs[4], rq[4];
  if ((tid & 63) == 0) { rs[tid >> 6] = s; rq[tid >> 6] = q; }
  __syncthreads();
  if (tid == 0) {
    outp[blk * 2] = rs[0] + rs[1] + rs[2] + rs[3];
    outp[blk * 2 + 1] = rq[0] + rq[1] + rq[2] + rq[3];
  }
}

__global__ void std_final(const float* __restrict__ part, float* __restrict__ invstd) {
  int b = threadIdx.x;
  if (b < B_) {
    double s = 0.0, q = 0.0;
    for (int i = 0; i < 64; i++) {
      s += (double)part[(b * 64 + i) * 2];
      q += (double)part[(b * 64 + i) * 2 + 1];
    }
    const double n = (double)(S_ * K_ * 67);
    double var = (q - s * s / n) / (n - 1.0);
    invstd[b] = (float)(1.0 / (sqrt(var) + 1e-5));
  }
}

template <int MODE>
__global__ __launch_bounds__(256, 2) void mlp_kernel(
    const float* __restrict__ feature, const float* __restrict__ xyz,
    const float* __restrict__ nxyz, const float* __restrict__ nfeat,
    const int* __restrict__ knn, const float* __restrict__ invstd,
    const float* __restrict__ alpha, const float* __restrict__ beta,
    const float* __restrict__ w_tr, const float* __restrict__ b_tr,
    const float* __restrict__ w1, const float* __restrict__ b1,
    const float* __restrict__ w2, const float* __restrict__ b2,
    const float* __restrict__ bn_tr, const float* __restrict__ bn_1,
    float* __restrict__ bnpart, float* __restrict__ out1) {
  __shared__ __align__(16) float pool[15556];
  float* Wt = pool;
  float* xin = pool + 8516;
  float* ub = xin;
  float* tb = pool + 8516 + 4192;
  float* part = pool + 8516 + 4192 + 2304;
  int* sknn = (int*)(part + 512);
  const int bs = blockIdx.x, tid = threadIdx.x;
  const int b = bs >> 10, s = bs & 1023;
  if (tid < K_) sknn[tid] = knn[(size_t)bs * K_ + tid];
  for (int e = tid; e < 64 * 131; e += 256) {
    int o = e / 131, c = e - o * 131;
    Wt[c * 65 + o] = w_tr[e];
  }
  __syncthreads();
  const float inv = invstd[b];
  for (int e = tid; e < CIN_ * K_; e += 256) {
    int c = e >> 5, kk = e & 31;
    float v;
    if (c < 67) {
      int n = sknn[kk];
      float raw = (c < 64) ? feature[((size_t)b * 64 + c) * N_ + n]
                           : xyz[((size_t)b * 3 + (c - 64)) * N_ + n];
      float anc = (c < 64) ? nfeat[(size_t)bs * 64 + c]
                           : nxyz[(size_t)bs * 3 + (c - 64)];
      v = alpha[c] * ((raw - anc) * inv) + beta[c];
    } else {
      v = nfeat[(size_t)bs * 64 + (c - 67)];
    }
    xin[e] = v;
  }
  __syncthreads();
  const int o = tid & 63, kkb = (tid >> 6) * 8;
  float acc[8];
  {
    float bv = b_tr[o];
#pragma unroll
    for (int j = 0; j < 8; j++) acc[j] = bv;
  }
  for (int c = 0; c < CIN_; c++) {
    float w = Wt[c * 65 + o];
    const float4 xa = *(const float4*)(xin + c * 32 + kkb);
    const float4 xb4 = *(const float4*)(xin + c * 32 + kkb + 4);
    acc[0] += w * xa.x; acc[1] += w * xa.y; acc[2] += w * xa.z; acc[3] += w * xa.w;
    acc[4] += w * xb4.x; acc[5] += w * xb4.y; acc[6] += w * xb4.z; acc[7] += w * xb4.w;
  }
  if (MODE == 0) {
    float s8 = 0.f, q8 = 0.f;
#pragma unroll
    for (int j = 0; j < 8; j++) { s8 += acc[j]; q8 += acc[j] * acc[j]; }
    part[(tid >> 6) * 64 + o] = s8;
    part[256 + (tid >> 6) * 64 + o] = q8;
    __syncthreads();
    if (tid < 64) {
      float ss = 0.f, qq = 0.f;
      for (int g = 0; g < 4; g++) { ss += part[g * 64 + tid]; qq += part[256 + g * 64 + tid]; }
      bnpart[(size_t)bs * 128 + tid] = ss;
      bnpart[(size_t)bs * 128 + 64 + tid] = qq;
    }
    return;
  }
  float tv[8];
  {
    float sc = bn_tr[o], sh = bn_tr[64 + o];
#pragma unroll
    for (int j = 0; j < 8; j++) {
      tv[j] = fmaxf(fmaf(sc, acc[j], sh), 0.f);
      tb[o * 36 + kkb + j] = tv[j];
    }
  }
  __syncthreads();
  for (int e = tid; e < 64 * 64; e += 256) {
    int oo = e >> 6, c = e & 63;
    Wt[c * 65 + oo] = w1[e];
  }
  __syncthreads();
  float acc2[8];
  {
    float bv = b1[o];
#pragma unroll
    for (int j = 0; j < 8; j++) acc2[j] = bv;
  }
  for (int c = 0; c < 64; c++) {
    float w = Wt[c * 65 + o];
    const float4 ta = *(const float4*)(tb + c * 36 + kkb);
    const float4 ta2 = *(const float4*)(tb + c * 36 + kkb + 4);
    acc2[0] += w * ta.x; acc2[1] += w * ta.y; acc2[2] += w * ta.z; acc2[3] += w * ta.w;
    acc2[4] += w * ta2.x; acc2[5] += w * ta2.y; acc2[6] += w * ta2.z; acc2[7] += w * ta2.w;
  }
  if (MODE == 1) {
    float s8 = 0.f, q8 = 0.f;
#pragma unroll
    for (int j = 0; j < 8; j++) { s8 += acc2[j]; q8 += acc2[j] * acc2[j]; }
    part[(tid >> 6) * 64 + o] = s8;
    part[256 + (tid >> 6) * 64 + o] = q8;
    __syncthreads();
    if (tid < 64) {
      float ss = 0.f, qq = 0.f;
      for (int g = 0; g < 4; g++) { ss += part[g * 64 + tid]; qq += part[256 + g * 64 + tid]; }
      bnpart[(size_t)bs * 128 + tid] = ss;
      bnpart[(size_t)bs * 128 + 64 + tid] = qq;
    }
    return;
  }
  {
    float sc = bn_1[o], sh = bn_1[64 + o];
#pragma unroll
    for (int j = 0; j < 8; j++) ub[o * 36 + kkb + j] = fmaxf(fmaf(sc, acc2[j], sh), 0.f);
  }
  __syncthreads();
  for (int e = tid; e < 64 * 64; e += 256) {
    int oo = e >> 6, c = e & 63;
    Wt[c * 65 + oo] = w2[e];
  }
  __syncthreads();
  float acc3[8];
  {
    float bv = b2[o];
#pragma unroll
    for (int j = 0; j < 8; j++) acc3[j] = bv;
  }
  for (int c = 0; c < 64; c++) {
    float w = Wt[c * 65 + o];
    const float4 ua = *(const float4*)(ub + c * 36 + kkb);
    const float4 ua2 = *(const float4*)(ub + c * 36 + kkb + 4);
    acc3[0] += w * ua.x; acc3[1] += w * ua.y; acc3[2] += w * ua.z; acc3[3] += w * ua.w;
    acc3[4] += w * ua2.x; acc3[5] += w * ua2.y; acc3[6] += w * ua2.z; acc3[7] += w * ua2.w;
  }
  float m = 0.f;
#pragma unroll
  for (int j = 0; j < 8; j++) m = fmaxf(m, fmaxf(acc3[j] + tv[j], 0.f));
  part[(tid >> 6) * 64 + o] = m;
  __syncthreads();
  if (tid < 64) {
    float mm = part[tid];
    for (int g = 1; g < 4; g++) mm = fmaxf(mm, part[g * 64 + tid]);
    out1[((size_t)b * 64 + tid) * S_ + s] = mm;
  }
}

// ---------------------------------------------------------------------------
// BN finalize (shared by both paths).
// ---------------------------------------------------------------------------
__global__ __launch_bounds__(256) void bn_finalize(const float* __restrict__ part,
                                                   const float* __restrict__ g,
                                                   const float* __restrict__ be,
                                                   float* __restrict__ bnout) {
  const int ch = blockIdx.x, tid = threadIdx.x;
  double s = 0.0, q = 0.0;
  for (int i = tid; i < B_ * S_; i += 256) {
    s += (double)part[(size_t)i * 128 + ch];
    q += (double)part[(size_t)i * 128 + 64 + ch];
  }
#pragma unroll
  for (int off = 32; off >= 1; off >>= 1) { s += __shfl_xor(s, off); q += __shfl_xor(q, off); }
  __shared__ double ls[4], lq[4];
  if ((tid & 63) == 0) { ls[tid >> 6] = s; lq[tid >> 6] = q; }
  __syncthreads();
  if (tid == 0) {
    double Ssum = ls[0] + ls[1] + ls[2] + ls[3];
    double Qsum = lq[0] + lq[1] + lq[2] + lq[3];
    const double n = (double)(B_ * S_ * K_);
    double mu = Ssum / n;
    double var = Qsum / n - mu * mu;
    double sc = (double)g[ch] / sqrt(var + 1e-5);
    bnout[ch] = (float)sc;
    bnout[64 + ch] = (float)((double)be[ch] - mu * sc);
  }
}

// ===========================================================================
// ================== CACHE-PATH kernels (large workspace) ===================
// ===========================================================================

// Fused diff computation + std partials. 1024 blocks x 8 groups.
__global__ __launch_bounds__(256) void prep_kernel(const float* __restrict__ featT,
                                                   const float* __restrict__ xyz,
                                                   const float* __restrict__ nxyz,
                                                   const float* __restrict__ nfeat,
                                                   const int* __restrict__ knn,
                                                   float* __restrict__ dcache,
                                                   float* __restrict__ outp) {
  const int blk = blockIdx.x, tid = threadIdx.x;
  __shared__ int sk[32];
  float s = 0.f, q = 0.f;
  const int c = tid & 63, qd = tid >> 6;
  for (int g = 0; g < 8; g++) {
    const int bs = blk * 8 + g, b = bs >> 10;
    if (tid < 32) sk[tid] = knn[(size_t)bs * K_ + tid];
    __syncthreads();
    float anc = nfeat[(size_t)bs * 64 + c];
#pragma unroll
    for (int it = 0; it < 8; it++) {
      int kk = it * 4 + qd;
      int n = sk[kk];
      float dd = featT[((size_t)b * N_ + n) * 64 + c] - anc;
      s += dd; q += dd * dd;
      dcache[((size_t)bs * 32 + kk) * 68 + c] = dd;
    }
    if (tid < 96) {
      int c3 = tid >> 5, kk = tid & 31;
      int n = sk[kk];
      float dd = xyz[((size_t)b * 3 + c3) * N_ + n] - nxyz[(size_t)bs * 3 + c3];
      s += dd; q += dd * dd;
      dcache[((size_t)bs * 32 + kk) * 68 + 64 + c3] = dd;
    }
    __syncthreads();
  }
#pragma unroll
  for (int off = 32; off >= 1; off >>= 1) { s += __shfl_xor(s, off); q += __shfl_xor(q, off); }
  __shared__ float rs[4], rq[4];
  if ((tid & 63) == 0) { rs[tid >> 6] = s; rq[tid >> 6] = q; }
  __syncthreads();
  if (tid == 0) {
    outp[blk * 2] = rs[0] + rs[1] + rs[2] + rs[3];
    outp[blk * 2 + 1] = rq[0] + rq[1] + rq[2] + rq[3];
  }
}

__global__ void std_final_c(const float* __restrict__ part, float* __restrict__ invstd) {
  int b = threadIdx.x;
  if (b < B_) {
    double s = 0.0, q = 0.0;
    for (int i = 0; i < 128; i++) {
      s += (double)part[(b * 128 + i) * 2];
      q += (double)part[(b * 128 + i) * 2 + 1];
    }
    const double n = (double)(S_ * K_ * 67);
    double var = (q - s * s / n) / (n - 1.0);
    invstd[b] = (float)(1.0 / (sqrt(var) + 1e-5));
  }
}

// MLP stage 0: xin from dcache (coalesced), conv_tr, stats + tcache store.
__global__ __launch_bounds__(256, 2) void mlp0c(
    const float* __restrict__ dcache, const float* __restrict__ nfeat,
    const float* __restrict__ invstd,
    const float* __restrict__ alpha, const float* __restrict__ beta,
    const float* __restrict__ w_tr, const float* __restrict__ b_tr,
    float* __restrict__ bnpart, float* __restrict__ tcache) {
  __shared__ __align__(16) float pool[13220];
  float* Wt = pool;
  float* xin = pool + 8516;
  float* part = pool + 8516 + 4192;
  const int bs = blockIdx.x, tid = threadIdx.x;
  const int b = bs >> 10;
  for (int e = tid; e < 64 * 131; e += 256) {
    int o = e / 131, c = e - o * 131;
    Wt[c * 65 + o] = w_tr[e];
  }
  const float inv = invstd[b];
  {
    const int c = tid & 63, qd = tid >> 6;
    float al = alpha[c], bev = beta[c];
#pragma unroll
    for (int it = 0; it < 8; it++) {
      int kk = it * 4 + qd;
      xin[c * 32 + kk] = al * (dcache[((size_t)bs * 32 + kk) * 68 + c] * inv) + bev;
    }
    if (tid < 96) {
      int c3 = 64 + (tid >> 5), kk = tid & 31;
      xin[c3 * 32 + kk] =
          alpha[c3] * (dcache[((size_t)bs * 32 + kk) * 68 + c3] * inv) + beta[c3];
    }
    for (int e = tid; e < 2048; e += 256) {
      int cc = 67 + (e >> 5), kk = e & 31;
      xin[cc * 32 + kk] = nfeat[(size_t)bs * 64 + (e >> 5)];
    }
  }
  __syncthreads();
  const int o = tid & 63, kkb = (tid >> 6) * 8;
  float acc[8];
  {
    float bv = b_tr[o];
#pragma unroll
    for (int j = 0; j < 8; j++) acc[j] = bv;
  }
  for (int c = 0; c < CIN_; c++) {
    float w = Wt[c * 65 + o];
    const float4 xa = *(const float4*)(xin + c * 32 + kkb);
    const float4 xb4 = *(const float4*)(xin + c * 32 + kkb + 4);
    acc[0] += w * xa.x; acc[1] += w * xa.y; acc[2] += w * xa.z; acc[3] += w * xa.w;
    acc[4] += w * xb4.x; acc[5] += w * xb4.y; acc[6] += w * xb4.z; acc[7] += w * xb4.w;
  }
  {
    float4* tp = (float4*)(tcache + ((size_t)bs * 64 + o) * 32 + kkb);
    tp[0] = make_float4(acc[0], acc[1], acc[2], acc[3]);
    tp[1] = make_float4(acc[4], acc[5], acc[6], acc[7]);
  }
  float s8 = 0.f, q8 = 0.f;
#pragma unroll
  for (int j = 0; j < 8; j++) { s8 += acc[j]; q8 += acc[j] * acc[j]; }
  part[(tid >> 6) * 64 + o] = s8;
  part[256 + (tid >> 6) * 64 + o] = q8;
  __syncthreads();
  if (tid < 64) {
    float ss = 0.f, qq = 0.f;
    for (int g = 0; g < 4; g++) { ss += part[g * 64 + tid]; qq += part[256 + g * 64 + tid]; }
    bnpart[(size_t)bs * 128 + tid] = ss;
    bnpart[(size_t)bs * 128 + 64 + tid] = qq;
  }
}

// MLP stage 1: t = bn+relu(tcache); conv1; stats + ucache store.
__global__ __launch_bounds__(256, 3) void mlp1c(
    const float* __restrict__ tcache, const float* __restrict__ bn_tr,
    const float* __restrict__ w1, const float* __restrict__ b1,
    float* __restrict__ bnpart, float* __restrict__ ucache) {
  __shared__ __align__(16) float pool[6976];
  float* Wt = pool;
  float* tb = pool + 4160;
  float* part = pool + 4160 + 2304;
  const int bs = blockIdx.x, tid = threadIdx.x;
  const int o = tid & 63, kkb = (tid >> 6) * 8;
  for (int e = tid; e < 64 * 64; e += 256) {
    int oo = e >> 6, c = e & 63;
    Wt[c * 65 + oo] = w1[e];
  }
  float t[8];
  {
    const float4* tp = (const float4*)(tcache + ((size_t)bs * 64 + o) * 32 + kkb);
    float4 a = tp[0], b4 = tp[1];
    t[0] = a.x; t[1] = a.y; t[2] = a.z; t[3] = a.w;
    t[4] = b4.x; t[5] = b4.y; t[6] = b4.z; t[7] = b4.w;
  }
  {
    float sc = bn_tr[o], sh = bn_tr[64 + o];
#pragma unroll
    for (int j = 0; j < 8; j++) tb[o * 36 + kkb + j] = fmaxf(fmaf(sc, t[j], sh), 0.f);
  }
  __syncthreads();
  float acc2[8];
  {
    float bv = b1[o];
#pragma unroll
    for (int j = 0; j < 8; j++) acc2[j] = bv;
  }
  for (int c = 0; c < 64; c++) {
    float w = Wt[c * 65 + o];
    const float4 ta = *(const float4*)(tb + c * 36 + kkb);
    const float4 ta2 = *(const float4*)(tb + c * 36 + kkb + 4);
    acc2[0] += w * ta.x; acc2[1] += w * ta.y; acc2[2] += w * ta.z; acc2[3] += w * ta.w;
    acc2[4] += w * ta2.x; acc2[5] += w * ta2.y; acc2[6] += w * ta2.z; acc2[7] += w * ta2.w;
  }
  {
    float4* up = (float4*)(ucache + ((size_t)bs * 64 + o) * 32 + kkb);
    up[0] = make_float4(acc2[0], acc2[1], acc2[2], acc2[3]);
    up[1] = make_float4(acc2[4], acc2[5], acc2[6], acc2[7]);
  }
  float s8 = 0.f, q8 = 0.f;
#pragma unroll
  for (int j = 0; j < 8; j++) { s8 += acc2[j]; q8 += acc2[j] * acc2[j]; }
  part[(tid >> 6) * 64 + o] = s8;
  part[256 + (tid >> 6) * 64 + o] = q8;
  __syncthreads();
  if (tid < 64) {
    float ss = 0.f, qq = 0.f;
    for (int g = 0; g < 4; g++) { ss += part[g * 64 + tid]; qq += part[256 + g * 64 + tid]; }
    bnpart[(size_t)bs * 128 + tid] = ss;
    bnpart[(size_t)bs * 128 + 64 + tid] = qq;
  }
}

// MLP stage 2: u = bn+relu(ucache); conv2; residual with bn+relu(tcache); max.
__global__ __launch_bounds__(256, 3) void mlp2c(
    const float* __restrict__ tcache, const float* __restrict__ ucache,
    const float* __restrict__ bn_tr, const float* __restrict__ bn_1,
    const float* __restrict__ w2, const float* __restrict__ b2,
    float* __restrict__ out1) {
  __shared__ __align__(16) float pool[6976];
  float* Wt = pool;
  float* ub = pool + 4160;
  float* part = pool + 4160 + 2304;
  const int bs = blockIdx.x, tid = threadIdx.x;
  const int b = bs >> 10, s = bs & 1023;
  const int o = tid & 63, kkb = (tid >> 6) * 8;
  for (int e = tid; e < 64 * 64; e += 256) {
    int oo = e >> 6, c = e & 63;
    Wt[c * 65 + oo] = w2[e];
  }
  {
    const float4* up = (const float4*)(ucache + ((size_t)bs * 64 + o) * 32 + kkb);
    float4 a = up[0], b4 = up[1];
    float u[8] = {a.x, a.y, a.z, a.w, b4.x, b4.y, b4.z, b4.w};
    float sc = bn_1[o], sh = bn_1[64 + o];
#pragma unroll
    for (int j = 0; j < 8; j++) ub[o * 36 + kkb + j] = fmaxf(fmaf(sc, u[j], sh), 0.f);
  }
  __syncthreads();
  float acc3[8];
  {
    float bv = b2[o];
#pragma unroll
    for (int j = 0; j < 8; j++) acc3[j] = bv;
  }
  for (int c = 0; c < 64; c++) {
    float w = Wt[c * 65 + o];
    const float4 ua = *(const float4*)(ub + c * 36 + kkb);
    const float4 ua2 = *(const float4*)(ub + c * 36 + kkb + 4);
    acc3[0] += w * ua.x; acc3[1] += w * ua.y; acc3[2] += w * ua.z; acc3[3] += w * ua.w;
    acc3[4] += w * ua2.x; acc3[5] += w * ua2.y; acc3[6] += w * ua2.z; acc3[7] += w * ua2.w;
  }
  float tv[8];
  {
    const float4* tp = (const float4*)(tcache + ((size_t)bs * 64 + o) * 32 + kkb);
    float4 a = tp[0], b4 = tp[1];
    float t[8] = {a.x, a.y, a.z, a.w, b4.x, b4.y, b4.z, b4.w};
    float sc = bn_tr[o], sh = bn_tr[64 + o];
#pragma unroll
    for (int j = 0; j < 8; j++) tv[j] = fmaxf(fmaf(sc, t[j], sh), 0.f);
  }
  float m = 0.f;
#pragma unroll
  for (int j = 0; j < 8; j++) m = fmaxf(m, fmaxf(acc3[j] + tv[j], 0.f));
  part[(tid >> 6) * 64 + o] = m;
  __syncthreads();
  if (tid < 64) {
    float mm = part[tid];
    for (int g = 1; g < 4; g++) mm = fmaxf(mm, part[g * 64 + tid]);
    out1[((size_t)b * 64 + tid) * S_ + s] = mm;
  }
}

// ---------------------------------------------------------------------------
extern "C" void kernel_launch(void* const* d_in, const int* in_sizes, int n_in,
                              void* d_out, int out_size, void* d_ws, size_t ws_size,
                              hipStream_t stream) {
  const float* xyz = (const float*)d_in[0];
  const float* feature = (const float*)d_in[1];
  const float* alpha = (const float*)d_in[2];
  const float* beta = (const float*)d_in[3];
  const float* w_tr = (const float*)d_in[4];
  const float* b_tr = (const float*)d_in[5];
  const float* g_tr = (const float*)d_in[6];
  const float* be_tr = (const float*)d_in[7];
  const float* w1 = (const float*)d_in[8];
  const float* b1 = (const float*)d_in[9];
  const float* g1 = (const float*)d_in[10];
  const float* be1 = (const float*)d_in[11];
  const float* w2 = (const float*)d_in[12];
  const float* b2 = (const float*)d_in[13];

  char* ws = (char*)d_ws;
  int* fps_i = (int*)(ws);                      // 32768 B
  float* nxyz = (float*)(ws + 32768);           // 98304 B
  float* nfeat = (float*)(ws + 131072);         // 2097152 B
  int* knn = (int*)(ws + 2228224);              // 1048576 B
  float* stdpart = (float*)(ws + 3276800);      // 4096 B (fallback)
  float* invstd = (float*)(ws + 3280896);       // 64 B
  float* bn_tr = (float*)(ws + 3280960);        // 512 B
  float* bn_1 = (float*)(ws + 3281472);         // 512 B
  float* bnpart = (float*)(ws + 3281984);       // 4194304 B -> end 7476288
  float* featT = (float*)(ws + 7476288);        // 8388608 B
  float* dcache = (float*)(ws + 15864896);      // 71303168 B
  float* tcache = (float*)(ws + 87168064);      // 67108864 B
  float* ucache = (float*)(ws + 154276928);     // 67108864 B
  float* stdpart_c = (float*)(ws + 221385792);  // 8192 B -> total 221393984

  float* out0 = (float*)d_out;
  float* out1 = out0 + B_ * 3 * S_;

  const bool big = (ws_size >= 221393984ull);

  if (big) {
    // fps blocks 0..7 + 512 fused-transpose blocks
    fps_kernel<<<8 + 512, 256, 0, stream>>>(xyz, fps_i, nxyz, out0, feature, featT);
    // knn blocks 0..8191 + 2048 fused anchor-gather blocks
    knn_kernel<<<8192 + 2048, 256, 0, stream>>>(xyz, nxyz, knn, featT, fps_i, nfeat);
    prep_kernel<<<1024, 256, 0, stream>>>(featT, xyz, nxyz, nfeat, knn, dcache, stdpart_c);
    std_final_c<<<1, 64, 0, stream>>>(stdpart_c, invstd);
    mlp0c<<<B_ * S_, 256, 0, stream>>>(dcache, nfeat, invstd, alpha, beta, w_tr, b_tr,
                                       bnpart, tcache);
    bn_finalize<<<64, 256, 0, stream>>>(bnpart, g_tr, be_tr, bn_tr);
    mlp1c<<<B_ * S_, 256, 0, stream>>>(tcache, bn_tr, w1, b1, bnpart, ucache);
    bn_finalize<<<64, 256, 0, stream>>>(bnpart, g1, be1, bn_1);
    mlp2c<<<B_ * S_, 256, 0, stream>>>(tcache, ucache, bn_tr, bn_1, w2, b2, out1);
  } else {
    fps_kernel<<<8, 256, 0, stream>>>(xyz, fps_i, nxyz, out0, feature, featT);
    gather_nf<<<(B_ * S_ * D_) / 256, 256, 0, stream>>>(feature, fps_i, nfeat);
    knn_kernel<<<8192, 256, 0, stream>>>(xyz, nxyz, knn, nullptr, nullptr, nullptr);
    std_partial<<<B_ * 64, 256, 0, stream>>>(feature, xyz, nxyz, nfeat, knn, stdpart);
    std_final<<<1, 64, 0, stream>>>(stdpart, invstd);
    mlp_kernel<0><<<B_ * S_, 256, 0, stream>>>(feature, xyz, nxyz, nfeat, knn, invstd,
                                               alpha, beta, w_tr, b_tr, w1, b1, w2, b2,
                                               bn_tr, bn_1, bnpart, out1);
    bn_finalize<<<64, 256, 0, stream>>>(bnpart, g_tr, be_tr, bn_tr);
    mlp_kernel<1><<<B_ * S_, 256, 0, stream>>>(feature, xyz, nxyz, nfeat, knn, invstd,
                                               alpha, beta, w_tr, b_tr, w1, b1, w2, b2,
                                               bn_tr, bn_1, bnpart, out1);
    bn_finalize<<<64, 256, 0, stream>>>(bnpart, g1, be1, bn_1);
    mlp_kernel<2><<<B_ * S_, 256, 0, stream>>>(feature, xyz, nxyz, nfeat, knn, invstd,
                                               alpha, beta, w_tr, b_tr, w1, b1, w2, b2,
                                               bn_tr, bn_1, bnpart, out1);
  }
}